// Round 14
// baseline (1044.694 us; speedup 1.0000x reference)
//
#include <hip/hip_runtime.h>
#include <hip/hip_fp16.h>

#define N_NODES 100000
#define N_EDGES 1600000
#define D 64
#define N_GRAPHS 64
#define NBLK ((N_NODES + 255) / 256)   // 391 scan blocks
#define WTS 68                         // WT row stride (floats): conflict-free
#define NS16 (N_NODES * 16)            // halfs per 16-feat slice (3.2 MB)
#define CH 64                          // rows per queue chunk
#define NCH ((N_NODES + CH - 1) / CH)  // 1563 chunks per slice

// ---------------- degree + in-edge count (deg starts at 0 via memset) -------
__global__ void k_count_deg(const int* __restrict__ dst, const float* __restrict__ ew,
                            float* __restrict__ deg, int* __restrict__ cnt) {
    int e = blockIdx.x * blockDim.x + threadIdx.x;
    if (e < N_EDGES) {
        int d = dst[e];
        atomicAdd(&deg[d], ew[e]);
        atomicAdd(&cnt[d], 1);
    }
}

// ---------------- dinv (fused, +1 self-loop) + scan of cnt ------------------
__global__ void k_scan1(const int* __restrict__ cnt, int* __restrict__ partial,
                        int* __restrict__ bsums, float* __restrict__ deg) {
    int t = threadIdx.x, b = blockIdx.x, i = b * 256 + t;
    if (i < N_NODES) {
        float d = deg[i];
        deg[i] = rsqrtf(d + 1.0f);    // self-loop weight 1 => always > 0
    }
    int v = (i < N_NODES) ? cnt[i] : 0;
    int incl = v;
    int lane = t & 63;
#pragma unroll
    for (int off = 1; off < 64; off <<= 1) {
        int u = __shfl_up(incl, off);
        if (lane >= off) incl += u;
    }
    __shared__ int wsum[4];
    int w = t >> 6;
    if (lane == 63) wsum[w] = incl;
    __syncthreads();
    int add = 0;
    for (int k = 0; k < w; ++k) add += wsum[k];
    incl += add;
    if (i < N_NODES) partial[i] = incl;
    if (t == 255) bsums[b] = incl;
}

__global__ void k_scan2(int* __restrict__ bsums) {
    __shared__ int s[512];
    int t = threadIdx.x;
    s[t] = (t < NBLK) ? bsums[t] : 0;
    __syncthreads();
    for (int off = 1; off < 512; off <<= 1) {
        int u = (t >= off) ? s[t - off] : 0;
        __syncthreads();
        s[t] += u;
        __syncthreads();
    }
    if (t < NBLK) bsums[t] = (t == 0) ? 0 : s[t - 1];  // exclusive
}

__global__ void k_scan3(const int* __restrict__ partial, const int* __restrict__ cnt,
                        const int* __restrict__ bsums, int* __restrict__ rowptr,
                        int* __restrict__ cursor) {
    int i = blockIdx.x * 256 + threadIdx.x;
    if (i < N_NODES) {
        int excl = partial[i] - cnt[i] + bsums[blockIdx.x];
        rowptr[i] = excl;
        cursor[i] = excl;
    }
}

// ---------------- scatter edges into CSR (src, norm) grouped by dst ----------
__global__ void k_scatter(const int* __restrict__ src, const int* __restrict__ dst,
                          const float* __restrict__ ew, const float* __restrict__ dinv,
                          int* __restrict__ cursor, float2* __restrict__ csr) {
    int e = blockIdx.x * blockDim.x + threadIdx.x;
    if (e < N_EDGES) {
        int s = src[e];
        int d = dst[e];
        float nrm = dinv[s] * ew[e] * dinv[d];
        int pos = atomicAdd(&cursor[d], 1);
        csr[pos] = make_float2(__int_as_float(s), nrm);
    }
}

// ---------------- x -> sliced fp16 table [4][N][16] ----------------
__global__ void k_half(const float* __restrict__ x, __half* __restrict__ xs) {
    int idx = blockIdx.x * blockDim.x + threadIdx.x;
    const int total = N_NODES * D;
    const int stride = gridDim.x * blockDim.x;
    for (; idx < total; idx += stride) {
        int node = idx >> 6, c = idx & 63;
        xs[(size_t)(c >> 4) * NS16 + node * 16 + (c & 15)] = __float2half_rn(x[idx]);
    }
}

// ---------------- XCD-local sliced aggregation ----------------
// The physical XCD id (s_getreg hwreg 20 = HW_REG_XCC_ID, verified on gfx950)
// selects the preferred feature-slice: slice tables are 3.2 MB fp16 -> fit the
// XCD's 4 MB L2, so gathers are L2-hits. Per-slice atomic chunk queues with
// work-stealing make correctness independent of the block->XCD distribution.
// Lane = (slot in [0,4))*16 + f: per 8 edges, 2 csr loads + 2 32B gathers.
__global__ __launch_bounds__(256) void k_agg(
        const __half* __restrict__ tabs, const float2* __restrict__ csr,
        const float* __restrict__ dinv, const int* __restrict__ rowptr,
        const int* __restrict__ cnt, float* __restrict__ agg,
        int* __restrict__ qcnt) {
    __shared__ int shc;
    int xcc;
    asm volatile("s_getreg_b32 %0, hwreg(20, 0, 32)" : "=s"(xcc));  // XCC_ID
    const int myslice = xcc & 3;
    const int lane = threadIdx.x & 63;
    const int wid  = threadIdx.x >> 6;
    const int slot = lane >> 4;          // 0..3 edge slot
    const int f    = lane & 15;          // 0..15 feature

    for (int qi = 0; qi < 4; ++qi) {
        const int q = (myslice + qi) & 3;
        const __half* __restrict__ tab = tabs + (size_t)q * NS16;
        for (;;) {
            __syncthreads();
            if (threadIdx.x == 0) shc = atomicAdd(&qcnt[q], 1);
            __syncthreads();
            const int ch = shc;
            if (ch >= NCH) break;
            const int rlo = ch * CH;
            const int rhi = rlo + CH < N_NODES ? rlo + CH : N_NODES;
            for (int row = rlo + wid; row < rhi; row += 4) {
                int st = __builtin_amdgcn_readfirstlane(rowptr[row]);
                int dg = __builtin_amdgcn_readfirstlane(cnt[row]);
                float di = dinv[row];
                float acc = (slot == 0)
                    ? __half2float(tab[row * 16 + f]) * (di * di) : 0.f;
                const int dgm1 = dg - 1;
                for (int j = 0; j < dg; j += 8) {
                    int e0 = j + slot, e1 = j + 4 + slot;
                    float2 c0 = csr[st + (e0 < dgm1 ? e0 : dgm1)];
                    float2 c1 = csr[st + (e1 < dgm1 ? e1 : dgm1)];
                    float w0 = (e0 < dg) ? c0.y : 0.f;
                    float w1 = (e1 < dg) ? c1.y : 0.f;
                    int i0 = __float_as_int(c0.x);
                    int i1 = __float_as_int(c1.x);
                    float v0 = __half2float(tab[i0 * 16 + f]);   // 32B L2-hit
                    float v1 = __half2float(tab[i1 * 16 + f]);
                    acc = fmaf(v0, w0, acc);
                    acc = fmaf(v1, w1, acc);
                }
                acc += __shfl_xor(acc, 16);   // fold 4 slots
                acc += __shfl_xor(acc, 32);
                if (slot == 0) agg[(size_t)row * D + q * 16 + f] = acc;
            }
        }
    }
}

// ---------------- dense GEMM + bias + relu ----------------
// MODE 0: write result as sliced fp16 (next layer's gather table).
// MODE 1: pool-atomicAdd into out[batch[row]].
template <int MODE>
__global__ __launch_bounds__(256) void k_gemm(
        const float* __restrict__ inrows, const float* __restrict__ W,
        const float* __restrict__ bias, const int* __restrict__ batch,
        __half* __restrict__ outh, float* __restrict__ outf) {
    __shared__ float WTs[D * WTS];
    __shared__ float aw[4][D];
    __shared__ float bs[D];
    {   // stage W transposed: WTs[c*WTS + k] = W[k*D + c]
        int t = threadIdx.x;
#pragma unroll
        for (int i = 0; i < 16; ++i) {
            int idx = t + i * 256;
            int k = idx >> 6, c = idx & 63;
            WTs[c * WTS + k] = W[idx];
        }
        if (t < D) bs[t] = bias[t];
    }
    __syncthreads();

    const int lane = threadIdx.x & 63;
    const int wid  = threadIdx.x >> 6;
    float* awm = aw[wid];
    const float bl = bs[lane];

    int gw = (blockIdx.x * blockDim.x + threadIdx.x) >> 6;
    const int tw = (gridDim.x * blockDim.x) >> 6;

    for (int row = gw; row < N_NODES; row += tw) {
        awm[lane] = inrows[(size_t)row * D + lane];
        float r0 = 0.f, r1 = 0.f, r2 = 0.f, r3 = 0.f;
#pragma unroll
        for (int t = 0; t < 16; ++t) {
            float4 a = *(const float4*)&awm[t * 4];                // broadcast
            float4 w = *(const float4*)&WTs[lane * WTS + t * 4];   // conflict-free
            r0 = fmaf(a.x, w.x, r0);
            r1 = fmaf(a.y, w.y, r1);
            r2 = fmaf(a.z, w.z, r2);
            r3 = fmaf(a.w, w.w, r3);
        }
        float r = fmaxf((r0 + r1) + (r2 + r3) + bl, 0.f);
        if (MODE == 0) {
            outh[(size_t)(lane >> 4) * NS16 + row * 16 + (lane & 15)] =
                __float2half_rn(r);
        } else {
            atomicAdd(&outf[batch[row] * D + lane], r);
        }
    }
}

// ---------------- finalize pool: divide by per-graph node count ----------------
__global__ void k_finalize(float* __restrict__ out, const int* __restrict__ batch) {
    int g = blockIdx.x;
    int lane = threadIdx.x;
    int lo = 0, hi = N_NODES;
    while (lo < hi) { int m = (lo + hi) >> 1; if (batch[m] < g) lo = m + 1; else hi = m; }
    int start = lo;
    hi = N_NODES;
    while (lo < hi) { int m = (lo + hi) >> 1; if (batch[m] < g + 1) lo = m + 1; else hi = m; }
    float c = (float)(lo - start);
    out[g * D + lane] /= fmaxf(c, 1.0f);
}

// ---------------- launch ----------------
extern "C" void kernel_launch(void* const* d_in, const int* in_sizes, int n_in,
                              void* d_out, int out_size, void* d_ws, size_t ws_size,
                              hipStream_t stream) {
    const float* x     = (const float*)d_in[0];
    const int*   ei    = (const int*)d_in[1];
    const int*   src   = ei;
    const int*   dst   = ei + N_EDGES;
    const int*   batch = (const int*)d_in[2];
    const float* ew    = (const float*)d_in[3];
    const float* W1    = (const float*)d_in[4];
    const float* b1    = (const float*)d_in[5];
    const float* W2    = (const float*)d_in[6];
    const float* b2    = (const float*)d_in[7];
    float* out = (float*)d_out;

    char* ws = (char*)d_ws;
    __half* xsh    = (__half*)(ws);                   // 12.8 MB sliced fp16 x
    __half* hh     = (__half*)(ws + 12800000);        // 12.8 MB sliced fp16 h1
    float*  agg    = (float*)(ws + 25600000);         // 25.6 MB f32 agg rows
    float2* csr    = (float2*)(ws + 51200000);        // 12.8 MB (src, norm)
    float*  deg    = (float*)(ws + 64000000);         // 400 KB  deg -> dinv
    int*    cnt    = (int*)(ws + 64400000);           // 400 KB
    int*    rowptr = (int*)(ws + 64800000);           // 400 KB
    int*    cursor = (int*)(ws + 65200000);           // 400 KB
    int*    bsums  = (int*)(ws + 65600000);           // 2 KB
    int*    qcnt   = (int*)(ws + 65604096);           // 8 queue counters

    // zero-init via async memset
    hipMemsetAsync(deg, 0, N_NODES * sizeof(float), stream);
    hipMemsetAsync(cnt, 0, N_NODES * sizeof(int), stream);
    hipMemsetAsync(out, 0, N_GRAPHS * D * sizeof(float), stream);
    hipMemsetAsync(qcnt, 0, 8 * sizeof(int), stream);

    // normalization + CSR build (+ sliced fp16 conversion of x, independent)
    k_half<<<1024, 256, 0, stream>>>(x, xsh);
    k_count_deg<<<(N_EDGES + 255) / 256, 256, 0, stream>>>(dst, ew, deg, cnt);
    k_scan1<<<NBLK, 256, 0, stream>>>(cnt, rowptr, bsums, deg);   // + fused dinv
    k_scan2<<<1, 512, 0, stream>>>(bsums);
    k_scan3<<<NBLK, 256, 0, stream>>>(rowptr, cnt, bsums, rowptr, cursor);
    k_scatter<<<(N_EDGES + 255) / 256, 256, 0, stream>>>(src, dst, ew, deg, cursor, csr);

    // layer 1: agg = A xh ; hh = fp16(relu(agg W1 + b1)) sliced
    k_agg<<<4096, 256, 0, stream>>>(xsh, csr, deg, rowptr, cnt, agg, qcnt);
    k_gemm<0><<<2048, 256, 0, stream>>>(agg, W1, b1, batch, hh, out);
    // layer 2: agg = A hh ; out[g] += relu(agg W2 + b2)
    k_agg<<<4096, 256, 0, stream>>>(hh, csr, deg, rowptr, cnt, agg, qcnt + 4);
    k_gemm<1><<<2048, 256, 0, stream>>>(agg, W2, b2, batch, hh, out);
    // mean
    k_finalize<<<N_GRAPHS, D, 0, stream>>>(out, batch);
}

// Round 15
// 511.078 us; speedup vs baseline: 2.0441x; 2.0441x over previous
//
#include <hip/hip_runtime.h>

#define N_NODES 100000
#define N_EDGES 1600000
#define D 64
#define N_GRAPHS 64
#define NBLK ((N_NODES + 255) / 256)   // 391 scan blocks
#define WTS 68                         // WT row stride (floats): conflict-free

// ---------------- degree + in-edge count (deg starts at 0 via memset) -------
__global__ void k_count_deg(const int* __restrict__ dst, const float* __restrict__ ew,
                            float* __restrict__ deg, int* __restrict__ cnt) {
    int e = blockIdx.x * blockDim.x + threadIdx.x;
    if (e < N_EDGES) {
        int d = dst[e];
        atomicAdd(&deg[d], ew[e]);
        atomicAdd(&cnt[d], 1);
    }
}

// ---------------- dinv (fused, +1 self-loop) + exclusive scan of cnt --------
__global__ void k_scan1(const int* __restrict__ cnt, int* __restrict__ partial,
                        int* __restrict__ bsums, float* __restrict__ deg) {
    int t = threadIdx.x, b = blockIdx.x, i = b * 256 + t;
    if (i < N_NODES) {
        float d = deg[i];
        deg[i] = rsqrtf(d + 1.0f);    // self-loop weight 1 => always > 0
    }
    int v = (i < N_NODES) ? cnt[i] : 0;
    int incl = v;
    int lane = t & 63;
#pragma unroll
    for (int off = 1; off < 64; off <<= 1) {
        int u = __shfl_up(incl, off);
        if (lane >= off) incl += u;
    }
    __shared__ int wsum[4];
    int w = t >> 6;
    if (lane == 63) wsum[w] = incl;
    __syncthreads();
    int add = 0;
    for (int k = 0; k < w; ++k) add += wsum[k];
    incl += add;
    if (i < N_NODES) partial[i] = incl;
    if (t == 255) bsums[b] = incl;
}

__global__ void k_scan2(int* __restrict__ bsums) {
    __shared__ int s[512];
    int t = threadIdx.x;
    s[t] = (t < NBLK) ? bsums[t] : 0;
    __syncthreads();
    for (int off = 1; off < 512; off <<= 1) {
        int u = (t >= off) ? s[t - off] : 0;
        __syncthreads();
        s[t] += u;
        __syncthreads();
    }
    if (t < NBLK) bsums[t] = (t == 0) ? 0 : s[t - 1];  // exclusive
}

__global__ void k_scan3(const int* __restrict__ partial, const int* __restrict__ cnt,
                        const int* __restrict__ bsums, int* __restrict__ rowptr,
                        int* __restrict__ cursor) {
    int i = blockIdx.x * 256 + threadIdx.x;
    if (i < N_NODES) {
        int excl = partial[i] - cnt[i] + bsums[blockIdx.x];
        rowptr[i] = excl;
        cursor[i] = excl;
    }
}

// ---------------- pre-scale gather table: xsc[i][c] = x[i][c] * dinv[i] -----
// (re-association: msg = (x[s]*dinv[s]) * ew, row aggregate scaled by dinv[d]
//  afterwards -> scatter needs NO random dinv gathers)
__global__ void k_prescale(const float* __restrict__ x, const float* __restrict__ dinv,
                           float* __restrict__ xsc) {
    int i = blockIdx.x * blockDim.x + threadIdx.x;
    const int total = N_NODES * 16;     // float4 units
    const int stride = gridDim.x * blockDim.x;
    const float4* x4 = (const float4*)x;
    float4* o4 = (float4*)xsc;
    for (; i < total; i += stride) {
        float di = dinv[i >> 4];
        float4 v = x4[i];
        v.x *= di; v.y *= di; v.z *= di; v.w *= di;
        o4[i] = v;
    }
}

// ---------------- scatter edges into CSR (src, ew) grouped by dst ----------
// no dinv reads: raw edge weight stored; normalization folded into table+row
__global__ void k_scatter(const int* __restrict__ src, const int* __restrict__ dst,
                          const float* __restrict__ ew,
                          int* __restrict__ cursor, float2* __restrict__ csr) {
    int e = blockIdx.x * blockDim.x + threadIdx.x;
    if (e < N_EDGES) {
        int s = src[e];
        int d = dst[e];
        int pos = atomicAdd(&cursor[d], 1);
        csr[pos] = make_float2(__int_as_float(s), ew[e]);
    }
}

// ---------------- fused layer (r7 proven structure, pre-scaled table) -------
// One row per wave-iteration, 1024-thread blocks. Fully-predicated unroll-8
// passes (clamped index, zeroed weight); 8 independent gathers in flight.
// acc = xsc[row] + sum ew*xsc[s]  (all entries pre-scaled by their dinv),
// then acc *= dinv[row] before the GEMM.
// GEMM: lane's W-column from transposed-W LDS (stride 68, conflict-free),
// acc broadcast via 1 ds_write + same-address float4 reads.
// LAYER==1: store relu(.)*dinv[row] (next layer's pre-scaled table).
// LAYER==2: pool-atomicAdd relu(.) into out[batch[row]].
template <int LAYER>
__global__ __launch_bounds__(1024) void k_layer(
        const float* __restrict__ in, const float* __restrict__ W,
        const float* __restrict__ bias, const float* __restrict__ dinv,
        const int* __restrict__ rowptr, const int* __restrict__ cnt,
        const float2* __restrict__ csr, const int* __restrict__ batch,
        float* __restrict__ outp) {
    __shared__ float WTs[D * WTS];       // 17408 B transposed W
    __shared__ float aw[16][D];          // 4 KB per-wave row staging
    __shared__ float bs[D];

    {   // stage W transposed: WTs[c*WTS + k] = W[k*D + c]
        int t = threadIdx.x;
#pragma unroll
        for (int i = 0; i < 4; ++i) {
            int idx = t + i * 1024;
            int k = idx >> 6, c = idx & 63;
            WTs[c * WTS + k] = W[idx];
        }
        if (t < D) bs[t] = bias[t];
    }
    __syncthreads();

    const int lane = threadIdx.x & 63;
    const int wid  = threadIdx.x >> 6;
    float* awm = aw[wid];
    const float bl = bs[lane];

    int gw = (blockIdx.x * blockDim.x + threadIdx.x) >> 6;
    const int tw = (gridDim.x * blockDim.x) >> 6;

    for (int row = gw; row < N_NODES; row += tw) {
        const int st = __builtin_amdgcn_readfirstlane(rowptr[row]);
        const int dg = __builtin_amdgcn_readfirstlane(cnt[row]);
        const int dgm1 = dg - 1;
        const float di = dinv[row];
        float acc = in[row * D + lane];   // self-loop (pre-scaled table)

        const int passes = (dg + 7) >> 3;
        for (int p = 0; p < passes; ++p) {
            const int j = p * 8;
            int  jj0 = j + 0, jj1 = j + 1, jj2 = j + 2, jj3 = j + 3;
            int  jj4 = j + 4, jj5 = j + 5, jj6 = j + 6, jj7 = j + 7;
            float2 e0 = csr[st + (jj0 < dgm1 ? jj0 : dgm1)];
            float2 e1 = csr[st + (jj1 < dgm1 ? jj1 : dgm1)];
            float2 e2 = csr[st + (jj2 < dgm1 ? jj2 : dgm1)];
            float2 e3 = csr[st + (jj3 < dgm1 ? jj3 : dgm1)];
            float2 e4 = csr[st + (jj4 < dgm1 ? jj4 : dgm1)];
            float2 e5 = csr[st + (jj5 < dgm1 ? jj5 : dgm1)];
            float2 e6 = csr[st + (jj6 < dgm1 ? jj6 : dgm1)];
            float2 e7 = csr[st + (jj7 < dgm1 ? jj7 : dgm1)];
            float w0 = (jj0 < dg) ? e0.y : 0.f;
            float w1 = (jj1 < dg) ? e1.y : 0.f;
            float w2 = (jj2 < dg) ? e2.y : 0.f;
            float w3 = (jj3 < dg) ? e3.y : 0.f;
            float w4 = (jj4 < dg) ? e4.y : 0.f;
            float w5 = (jj5 < dg) ? e5.y : 0.f;
            float w6 = (jj6 < dg) ? e6.y : 0.f;
            float w7 = (jj7 < dg) ? e7.y : 0.f;
            int s0 = __builtin_amdgcn_readfirstlane(__float_as_int(e0.x));
            int s1 = __builtin_amdgcn_readfirstlane(__float_as_int(e1.x));
            int s2 = __builtin_amdgcn_readfirstlane(__float_as_int(e2.x));
            int s3 = __builtin_amdgcn_readfirstlane(__float_as_int(e3.x));
            int s4 = __builtin_amdgcn_readfirstlane(__float_as_int(e4.x));
            int s5 = __builtin_amdgcn_readfirstlane(__float_as_int(e5.x));
            int s6 = __builtin_amdgcn_readfirstlane(__float_as_int(e6.x));
            int s7 = __builtin_amdgcn_readfirstlane(__float_as_int(e7.x));
            float v0 = in[s0 * D + lane];
            float v1 = in[s1 * D + lane];
            float v2 = in[s2 * D + lane];
            float v3 = in[s3 * D + lane];
            float v4 = in[s4 * D + lane];
            float v5 = in[s5 * D + lane];
            float v6 = in[s6 * D + lane];
            float v7 = in[s7 * D + lane];
            acc = fmaf(v0, w0, acc);
            acc = fmaf(v1, w1, acc);
            acc = fmaf(v2, w2, acc);
            acc = fmaf(v3, w3, acc);
            acc = fmaf(v4, w4, acc);
            acc = fmaf(v5, w5, acc);
            acc = fmaf(v6, w6, acc);
            acc = fmaf(v7, w7, acc);
        }

        acc *= di;   // row-side normalization (re-association)

        // ---- GEMM: r[lane] = sum_k acc[k] * W[k][lane] ----
        awm[lane] = acc;   // same-wave LDS RAW; compiler inserts lgkmcnt wait
        float r0 = 0.f, r1 = 0.f, r2 = 0.f, r3 = 0.f;
#pragma unroll
        for (int t = 0; t < 16; ++t) {
            float4 a = *(const float4*)&awm[t * 4];                // broadcast
            float4 w = *(const float4*)&WTs[lane * WTS + t * 4];   // conflict-free
            r0 = fmaf(a.x, w.x, r0);
            r1 = fmaf(a.y, w.y, r1);
            r2 = fmaf(a.z, w.z, r2);
            r3 = fmaf(a.w, w.w, r3);
        }
        float r = fmaxf((r0 + r1) + (r2 + r3) + bl, 0.f);

        if (LAYER == 1) {
            outp[row * D + lane] = r * di;   // pre-scaled table for layer 2
        } else {
            atomicAdd(&outp[batch[row] * D + lane], r);
        }
    }
}

// ---------------- finalize pool: divide by per-graph node count ----------------
__global__ void k_finalize(float* __restrict__ out, const int* __restrict__ batch) {
    int g = blockIdx.x;
    int lane = threadIdx.x;
    int lo = 0, hi = N_NODES;
    while (lo < hi) { int m = (lo + hi) >> 1; if (batch[m] < g) lo = m + 1; else hi = m; }
    int start = lo;
    hi = N_NODES;
    while (lo < hi) { int m = (lo + hi) >> 1; if (batch[m] < g + 1) lo = m + 1; else hi = m; }
    float c = (float)(lo - start);
    out[g * D + lane] /= fmaxf(c, 1.0f);
}

// ---------------- launch ----------------
extern "C" void kernel_launch(void* const* d_in, const int* in_sizes, int n_in,
                              void* d_out, int out_size, void* d_ws, size_t ws_size,
                              hipStream_t stream) {
    const float* x     = (const float*)d_in[0];
    const int*   ei    = (const int*)d_in[1];
    const int*   src   = ei;
    const int*   dst   = ei + N_EDGES;
    const int*   batch = (const int*)d_in[2];
    const float* ew    = (const float*)d_in[3];
    const float* W1    = (const float*)d_in[4];
    const float* b1    = (const float*)d_in[5];
    const float* W2    = (const float*)d_in[6];
    const float* b2    = (const float*)d_in[7];
    float* out = (float*)d_out;

    char* ws = (char*)d_ws;
    float*  xsc    = (float*)(ws);                    // 25.6 MB pre-scaled x
    float*  hsc    = (float*)(ws + 25600000);         // 25.6 MB pre-scaled h1
    float2* csr    = (float2*)(ws + 51200000);        // 12.8 MB (src, ew)
    float*  deg    = (float*)(ws + 64000000);         // 400 KB  deg -> dinv
    int*    cnt    = (int*)(ws + 64400000);           // 400 KB
    int*    rowptr = (int*)(ws + 64800000);           // 400 KB
    int*    cursor = (int*)(ws + 65200000);           // 400 KB
    int*    bsums  = (int*)(ws + 65600000);           // 2 KB

    // zero-init via async memset (deg accumulates from 0; dinv adds self-loop)
    hipMemsetAsync(deg, 0, N_NODES * sizeof(float), stream);
    hipMemsetAsync(cnt, 0, N_NODES * sizeof(int), stream);
    hipMemsetAsync(out, 0, N_GRAPHS * D * sizeof(float), stream);

    // normalization + CSR build (CSR stores raw (src, ew): no dinv gathers)
    k_count_deg<<<(N_EDGES + 255) / 256, 256, 0, stream>>>(dst, ew, deg, cnt);
    k_scan1<<<NBLK, 256, 0, stream>>>(cnt, rowptr, bsums, deg);   // + fused dinv
    k_scan2<<<1, 512, 0, stream>>>(bsums);
    k_scan3<<<NBLK, 256, 0, stream>>>(rowptr, cnt, bsums, rowptr, cursor);
    k_prescale<<<2048, 256, 0, stream>>>(x, deg, xsc);
    k_scatter<<<(N_EDGES + 255) / 256, 256, 0, stream>>>(src, dst, ew, cursor, csr);

    // layer 1: hsc = relu((A xsc)*dinv W1 + b1) * dinv   (pre-scaled table)
    k_layer<1><<<512, 1024, 0, stream>>>(xsc, W1, b1, deg, rowptr, cnt, csr, batch, hsc);
    // layer 2 + pool-sum: out[g] += relu((A hsc)*dinv W2 + b2)
    k_layer<2><<<512, 1024, 0, stream>>>(hsc, W2, b2, deg, rowptr, cnt, csr, batch, out);
    // mean
    k_finalize<<<N_GRAPHS, D, 0, stream>>>(out, batch);
}

// Round 16
// 472.713 us; speedup vs baseline: 2.2100x; 1.0812x over previous
//
#include <hip/hip_runtime.h>
#include <hip/hip_fp16.h>

#define N_NODES 100000
#define N_EDGES 1600000
#define D 64
#define N_GRAPHS 64
#define NBLK ((N_NODES + 255) / 256)   // 391 scan blocks
#define WTS 68                         // WT row stride (floats): conflict-free

// ---------------- degree + in-edge count (deg starts at 0 via memset) -------
__global__ void k_count_deg(const int* __restrict__ dst, const float* __restrict__ ew,
                            float* __restrict__ deg, int* __restrict__ cnt) {
    int e = blockIdx.x * blockDim.x + threadIdx.x;
    if (e < N_EDGES) {
        int d = dst[e];
        atomicAdd(&deg[d], ew[e]);
        atomicAdd(&cnt[d], 1);
    }
}

// ---------------- dinv (fused, +1 self-loop) + exclusive scan of cnt --------
__global__ void k_scan1(const int* __restrict__ cnt, int* __restrict__ partial,
                        int* __restrict__ bsums, float* __restrict__ deg) {
    int t = threadIdx.x, b = blockIdx.x, i = b * 256 + t;
    if (i < N_NODES) {
        float d = deg[i];
        deg[i] = rsqrtf(d + 1.0f);    // self-loop weight 1 => always > 0
    }
    int v = (i < N_NODES) ? cnt[i] : 0;
    int incl = v;
    int lane = t & 63;
#pragma unroll
    for (int off = 1; off < 64; off <<= 1) {
        int u = __shfl_up(incl, off);
        if (lane >= off) incl += u;
    }
    __shared__ int wsum[4];
    int w = t >> 6;
    if (lane == 63) wsum[w] = incl;
    __syncthreads();
    int add = 0;
    for (int k = 0; k < w; ++k) add += wsum[k];
    incl += add;
    if (i < N_NODES) partial[i] = incl;
    if (t == 255) bsums[b] = incl;
}

__global__ void k_scan2(int* __restrict__ bsums) {
    __shared__ int s[512];
    int t = threadIdx.x;
    s[t] = (t < NBLK) ? bsums[t] : 0;
    __syncthreads();
    for (int off = 1; off < 512; off <<= 1) {
        int u = (t >= off) ? s[t - off] : 0;
        __syncthreads();
        s[t] += u;
        __syncthreads();
    }
    if (t < NBLK) bsums[t] = (t == 0) ? 0 : s[t - 1];  // exclusive
}

__global__ void k_scan3(const int* __restrict__ partial, const int* __restrict__ cnt,
                        const int* __restrict__ bsums, int* __restrict__ rowptr,
                        int* __restrict__ cursor) {
    int i = blockIdx.x * 256 + threadIdx.x;
    if (i < N_NODES) {
        int excl = partial[i] - cnt[i] + bsums[blockIdx.x];
        rowptr[i] = excl;
        cursor[i] = excl;
    }
}

// ---------------- scatter edges into CSR (src, norm) grouped by dst ----------
__global__ void k_scatter(const int* __restrict__ src, const int* __restrict__ dst,
                          const float* __restrict__ ew, const float* __restrict__ dinv,
                          int* __restrict__ cursor, float2* __restrict__ csr) {
    int e = blockIdx.x * blockDim.x + threadIdx.x;
    if (e < N_EDGES) {
        int s = src[e];
        int d = dst[e];
        float nrm = dinv[s] * ew[e] * dinv[d];
        int pos = atomicAdd(&cursor[d], 1);
        csr[pos] = make_float2(__int_as_float(s), nrm);
    }
}

// ---------------- x -> fp16 table [N][64] ----------------
__global__ void k_half(const float* __restrict__ x, __half* __restrict__ xh) {
    int i = blockIdx.x * blockDim.x + threadIdx.x;
    const int total = N_NODES * D / 4;
    const int stride = gridDim.x * blockDim.x;
    const float4* x4 = (const float4*)x;
    __half2* xh2 = (__half2*)xh;
    for (; i < total; i += stride) {
        float4 v = x4[i];
        xh2[2 * i + 0] = __floats2half2_rn(v.x, v.y);
        xh2[2 * i + 1] = __floats2half2_rn(v.z, v.w);
    }
}

// ---------------- fused layer: fp16 table + float4-grouped gathers ----------
// Dual-wall attack: fp16 halves bytes/edge (128 B rows) AND the r12 slot/q
// grouping quarters gather instructions (one 64-lane uint2 instruction covers
// 4 edges). lane = (slot in [0,4))*16 + q, q in [0,16): lane covers feats
// [4q, 4q+4) of its slot's edge. Per 16-edge pass: 1 csr load + 8 shfl +
// 4 gathers. Slot-fold: 8 shfl_xor; lanes of slot 0 stage the row to LDS.
// GEMM f32 (transposed-W LDS, stride 68) unchanged.
// LAYER==1: store row as fp16 (next table). LAYER==2: f32 pool-atomicAdd.
template <int LAYER>
__global__ __launch_bounds__(256) void k_layer(
        const __half* __restrict__ in, const float* __restrict__ W,
        const float* __restrict__ bias, const float* __restrict__ dinv,
        const int* __restrict__ rowptr, const int* __restrict__ cnt,
        const float2* __restrict__ csr, const int* __restrict__ batch,
        __half* __restrict__ outh, float* __restrict__ outf) {
    __shared__ float WTs[D * WTS];       // 17408 B transposed W
    __shared__ float aw[4][D];           // per-wave row staging
    __shared__ float bs[D];

    {   // stage W transposed: WTs[c*WTS + k] = W[k*D + c]
        int t = threadIdx.x;
#pragma unroll
        for (int i = 0; i < 16; ++i) {
            int idx = t + i * 256;
            int k = idx >> 6, c = idx & 63;
            WTs[c * WTS + k] = W[idx];
        }
        if (t < D) bs[t] = bias[t];
    }
    __syncthreads();

    const int lane = threadIdx.x & 63;
    const int wid  = threadIdx.x >> 6;
    const int slot = lane >> 4;          // 0..3
    const int q    = lane & 15;          // 0..15
    float* awm = aw[wid];
    const float bl = bs[lane];
    const uint2* in2 = (const uint2*)in; // row i = in2[i*16 .. i*16+15]

    int gw = (blockIdx.x * blockDim.x + threadIdx.x) >> 6;
    const int tw = (gridDim.x * blockDim.x) >> 6;

    for (int row = gw; row < N_NODES; row += tw) {
        const int st = __builtin_amdgcn_readfirstlane(rowptr[row]);
        const int dg = __builtin_amdgcn_readfirstlane(cnt[row]);
        const int cl = dg > 0 ? dg - 1 : 0;   // clamp index (safe for dg==0)

        float4 acc = make_float4(0.f, 0.f, 0.f, 0.f);
        {   // self-loop on slot 0
            if (slot == 0) {
                float di = dinv[row];
                float d2 = di * di;
                uint2 v = in2[row * 16 + q];
                __half2 h0 = *(__half2*)&v.x;
                __half2 h1 = *(__half2*)&v.y;
                float2 f0 = __half22float2(h0);
                float2 f1 = __half22float2(h1);
                acc.x = f0.x * d2; acc.y = f0.y * d2;
                acc.z = f1.x * d2; acc.w = f1.y * d2;
            }
        }

        for (int j = 0; j < dg; j += 16) {
            // one per-lane csr load covers 16 edges (4x slot redundancy)
            int ie = j + q;
            float2 c = csr[st + (ie < cl ? ie : cl)];
            // distribute: slot handles edges j+4k+slot (entry in lane 4k+slot)
            float sx0 = __shfl(c.x, 4 * 0 + slot);
            float wv0 = __shfl(c.y, 4 * 0 + slot);
            float sx1 = __shfl(c.x, 4 * 1 + slot);
            float wv1 = __shfl(c.y, 4 * 1 + slot);
            float sx2 = __shfl(c.x, 4 * 2 + slot);
            float wv2 = __shfl(c.y, 4 * 2 + slot);
            float sx3 = __shfl(c.x, 4 * 3 + slot);
            float wv3 = __shfl(c.y, 4 * 3 + slot);
            wv0 = (j + 0  + slot < dg) ? wv0 : 0.f;
            wv1 = (j + 4  + slot < dg) ? wv1 : 0.f;
            wv2 = (j + 8  + slot < dg) ? wv2 : 0.f;
            wv3 = (j + 12 + slot < dg) ? wv3 : 0.f;
            int i0 = __float_as_int(sx0);
            int i1 = __float_as_int(sx1);
            int i2 = __float_as_int(sx2);
            int i3 = __float_as_int(sx3);
            // 4 uint2 gathers: each instruction covers 4 fp16 rows (512 B)
            uint2 v0 = in2[i0 * 16 + q];
            uint2 v1 = in2[i1 * 16 + q];
            uint2 v2 = in2[i2 * 16 + q];
            uint2 v3 = in2[i3 * 16 + q];
            {
                float2 f0 = __half22float2(*(__half2*)&v0.x);
                float2 f1 = __half22float2(*(__half2*)&v0.y);
                acc.x = fmaf(f0.x, wv0, acc.x); acc.y = fmaf(f0.y, wv0, acc.y);
                acc.z = fmaf(f1.x, wv0, acc.z); acc.w = fmaf(f1.y, wv0, acc.w);
            }
            {
                float2 f0 = __half22float2(*(__half2*)&v1.x);
                float2 f1 = __half22float2(*(__half2*)&v1.y);
                acc.x = fmaf(f0.x, wv1, acc.x); acc.y = fmaf(f0.y, wv1, acc.y);
                acc.z = fmaf(f1.x, wv1, acc.z); acc.w = fmaf(f1.y, wv1, acc.w);
            }
            {
                float2 f0 = __half22float2(*(__half2*)&v2.x);
                float2 f1 = __half22float2(*(__half2*)&v2.y);
                acc.x = fmaf(f0.x, wv2, acc.x); acc.y = fmaf(f0.y, wv2, acc.y);
                acc.z = fmaf(f1.x, wv2, acc.z); acc.w = fmaf(f1.y, wv2, acc.w);
            }
            {
                float2 f0 = __half22float2(*(__half2*)&v3.x);
                float2 f1 = __half22float2(*(__half2*)&v3.y);
                acc.x = fmaf(f0.x, wv3, acc.x); acc.y = fmaf(f0.y, wv3, acc.y);
                acc.z = fmaf(f1.x, wv3, acc.z); acc.w = fmaf(f1.y, wv3, acc.w);
            }
        }

        // fold the 4 slots (same q): slot 0 ends with the row
        acc.x += __shfl_xor(acc.x, 16); acc.y += __shfl_xor(acc.y, 16);
        acc.z += __shfl_xor(acc.z, 16); acc.w += __shfl_xor(acc.w, 16);
        acc.x += __shfl_xor(acc.x, 32); acc.y += __shfl_xor(acc.y, 32);
        acc.z += __shfl_xor(acc.z, 32); acc.w += __shfl_xor(acc.w, 32);
        if (slot == 0) *(float4*)&awm[q * 4] = acc;
        // same-wave LDS RAW: in-order LDS pipe, no barrier needed

        // ---- GEMM: r[lane] = sum_k aw[k] * W[k][lane] ----
        float r0 = 0.f, r1 = 0.f, r2 = 0.f, r3 = 0.f;
#pragma unroll
        for (int t = 0; t < 16; ++t) {
            float4 a = *(const float4*)&awm[t * 4];                // broadcast
            float4 w = *(const float4*)&WTs[lane * WTS + t * 4];   // conflict-free
            r0 = fmaf(a.x, w.x, r0);
            r1 = fmaf(a.y, w.y, r1);
            r2 = fmaf(a.z, w.z, r2);
            r3 = fmaf(a.w, w.w, r3);
        }
        float r = fmaxf((r0 + r1) + (r2 + r3) + bl, 0.f);

        if (LAYER == 1) {
            outh[row * D + lane] = __float2half_rn(r);   // fp16 table for L2
        } else {
            atomicAdd(&outf[batch[row] * D + lane], r);
        }
    }
}

// ---------------- finalize pool: divide by per-graph node count ----------------
__global__ void k_finalize(float* __restrict__ out, const int* __restrict__ batch) {
    int g = blockIdx.x;
    int lane = threadIdx.x;
    int lo = 0, hi = N_NODES;
    while (lo < hi) { int m = (lo + hi) >> 1; if (batch[m] < g) lo = m + 1; else hi = m; }
    int start = lo;
    hi = N_NODES;
    while (lo < hi) { int m = (lo + hi) >> 1; if (batch[m] < g + 1) lo = m + 1; else hi = m; }
    float c = (float)(lo - start);
    out[g * D + lane] /= fmaxf(c, 1.0f);
}

// ---------------- launch ----------------
extern "C" void kernel_launch(void* const* d_in, const int* in_sizes, int n_in,
                              void* d_out, int out_size, void* d_ws, size_t ws_size,
                              hipStream_t stream) {
    const float* x     = (const float*)d_in[0];
    const int*   ei    = (const int*)d_in[1];
    const int*   src   = ei;
    const int*   dst   = ei + N_EDGES;
    const int*   batch = (const int*)d_in[2];
    const float* ew    = (const float*)d_in[3];
    const float* W1    = (const float*)d_in[4];
    const float* b1    = (const float*)d_in[5];
    const float* W2    = (const float*)d_in[6];
    const float* b2    = (const float*)d_in[7];
    float* out = (float*)d_out;

    char* ws = (char*)d_ws;
    __half* xh     = (__half*)(ws);                   // 12.8 MB fp16 x
    __half* hh     = (__half*)(ws + 12800000);        // 12.8 MB fp16 h1
    float2* csr    = (float2*)(ws + 25600000);        // 12.8 MB (src, norm)
    float*  deg    = (float*)(ws + 38400000);         // 400 KB  deg -> dinv
    int*    cnt    = (int*)(ws + 38800000);           // 400 KB
    int*    rowptr = (int*)(ws + 39200000);           // 400 KB
    int*    cursor = (int*)(ws + 39600000);           // 400 KB
    int*    bsums  = (int*)(ws + 40000000);           // 2 KB

    // zero-init via async memset (deg accumulates from 0; dinv adds self-loop)
    hipMemsetAsync(deg, 0, N_NODES * sizeof(float), stream);
    hipMemsetAsync(cnt, 0, N_NODES * sizeof(int), stream);
    hipMemsetAsync(out, 0, N_GRAPHS * D * sizeof(float), stream);

    // normalization + CSR build (+ fp16 conversion of x, independent)
    k_half<<<1024, 256, 0, stream>>>(x, xh);
    k_count_deg<<<(N_EDGES + 255) / 256, 256, 0, stream>>>(dst, ew, deg, cnt);
    k_scan1<<<NBLK, 256, 0, stream>>>(cnt, rowptr, bsums, deg);   // + fused dinv
    k_scan2<<<1, 512, 0, stream>>>(bsums);
    k_scan3<<<NBLK, 256, 0, stream>>>(rowptr, cnt, bsums, rowptr, cursor);
    k_scatter<<<(N_EDGES + 255) / 256, 256, 0, stream>>>(src, dst, ew, deg, cursor, csr);

    // layer 1: hh = fp16(relu((A xh) W1 + b1))
    k_layer<1><<<2048, 256, 0, stream>>>(xh, W1, b1, deg, rowptr, cnt, csr, batch, hh, out);
    // layer 2 + pool-sum: out[g] += relu((A hh) W2 + b2)
    k_layer<2><<<2048, 256, 0, stream>>>(hh, W2, b2, deg, rowptr, cnt, csr, batch, hh, out);
    // mean
    k_finalize<<<N_GRAPHS, D, 0, stream>>>(out, batch);
}